// Round 8
// baseline (58.754 us; speedup 1.0000x reference)
//
#include <hip/hip_runtime.h>
#include <hip/hip_bf16.h>
#include <math.h>

// Problem constants
#define BB 8
#define NN 1024
#define TT 512
#define KK 9
#define HH 32

#define NCHUNK 32          // n-chunks (grid.x)
#define NPER   (NN/NCHUNK) // 32 n per chunk (2 groups of 16)

#define PARTIAL_FLOATS ((size_t)NCHUNK * BB * KK * TT)   // 4.7 MB

__constant__ float c_epos[KK][3] = {
    { 0.30f,  0.25f, 0.00f},
    {-0.30f,  0.25f, 0.00f},
    {-0.05f, -0.40f, 0.00f},
    { 0.03f,  0.05f, 0.20f},
    { 0.00f,  0.05f, 0.22f},
    {-0.04f,  0.01f, 0.21f},
    {-0.08f, -0.02f, 0.18f},
    {-0.14f, -0.02f, 0.13f},
    {-0.20f, -0.02f, 0.07f},
};

// Single fused kernel. Block (chunk, b), 512 threads = 2 n-groups x 256 t-pairs.
//  1. MLP -> A coefficients for 32 n into LDS (1x, no redundancy)
//  2. env dot-product -> partial[chunk,b,k,t]
//  3. release: fence + device-scope counter[b]++
//  4. blocks chunk<16: acquire-spin until counter[b]==32, then finalize
//     t-slice [chunk*32, chunk*32+32): reduce 32 chunks, clip, leads, store.
// All 256 blocks are co-resident (1 block/CU max by grid size), so the spin
// cannot deadlock; a bounded guard degrades instead of hanging regardless.
__global__ __launch_bounds__(512) void fused_kernel(
    const float* __restrict__ pos,   // (B,N,3)
    const float* __restrict__ dd,    // (B,N,3)
    const float* __restrict__ amp,   // (B,N)
    const float* __restrict__ env,   // (B,N,T)
    const float* __restrict__ eoff,  // (B,K,3)
    const float* __restrict__ W1,    // (H,7)
    const float* __restrict__ pb1,   // (H)
    const float* __restrict__ W2,    // (1,H)
    const float* __restrict__ pb2,   // (1)
    float* __restrict__ partial,     // (NCHUNK,B,K,T) in ws
    unsigned int* __restrict__ counter, // (B) in ws, zeroed by memset node
    float* __restrict__ out)         // v_leads (B,12,T) ++ V_elec (B,K,T)
{
    const int tid   = threadIdx.x;
    const int chunk = blockIdx.x;
    const int b     = blockIdx.y;
    const int n0    = chunk * NPER;
    const int ng    = tid >> 8;      // n-group 0/1 (16 n each)
    const int tp    = tid & 255;     // t-pair index (t = 2*tp, 2*tp+1)

    __shared__ float sW1[HH * 7];
    __shared__ float sb1[HH];
    __shared__ float sW2[HH];
    __shared__ float sb2;
    __shared__ float sE[KK][3];
    __shared__ float sA[NPER][12];       // 9 coeffs padded to 12 for float4 reads
    __shared__ float2 sP[2][KK][256];    // cross-group reduce, 36 KB
    __shared__ float4 sV[NCHUNK][KK][8]; // finalize staging, 36 KB
    __shared__ float  sRf[KK][32];

    if (tid < HH * 7) sW1[tid] = W1[tid];
    if (tid < HH)     { sb1[tid] = pb1[tid]; sW2[tid] = W2[tid]; }
    if (tid < KK * 3) sE[tid / 3][tid % 3] = c_epos[tid / 3][tid % 3] + eoff[b * KK * 3 + tid];
    if (tid == 0)     sb2 = pb2[0];

    // ---- env register prefetch (independent of MLP -> overlaps it) ----
    const float2* envp = (const float2*)(env + ((size_t)(b * NN + n0 + ng * 16)) * TT) + tp;
    float2 pf[8];
    #pragma unroll
    for (int i = 0; i < 8; ++i) pf[i] = envp[(size_t)i * (TT / 2)];

    __syncthreads();   // weights + sE visible

    if (tid < NPER * KK) {           // 288 MLP evals, one per thread, 1x total
        const int k  = tid % KK;
        const int nl = tid / KK;
        const int bn = b * NN + n0 + nl;

        const float px = pos[bn * 3 + 0];
        const float py = pos[bn * 3 + 1];
        const float pz = pos[bn * 3 + 2];

        const float rx = sE[k][0] - px, ry = sE[k][1] - py, rz = sE[k][2] - pz;
        const float r2 = rx * rx + ry * ry + rz * rz;
        const float d0 = r2 + 0.04f;
        const float denom = d0 * sqrtf(d0);

        const float rdist = fmaxf(sqrtf(r2), 1e-6f);
        const float rinv  = 1.0f / rdist;
        float feat[7];
        feat[0] = px; feat[1] = py; feat[2] = pz;
        feat[3] = rx * rinv; feat[4] = ry * rinv; feat[5] = rz * rinv;
        feat[6] = rdist;

        float raw = sb2;
        #pragma unroll
        for (int j = 0; j < HH; ++j) {
            float s = sb1[j];
            #pragma unroll
            for (int f = 0; f < 7; ++f) s += sW1[j * 7 + f] * feat[f];
            const float g = 0.5f * s * (1.0f + erff(s * 0.70710678118654752f));
            raw += sW2[j] * g;
        }
        const float corr = 1.0f + 0.5f * tanhf(raw);

        const float ddx = dd[bn * 3 + 0], ddy = dd[bn * 3 + 1], ddz = dd[bn * 3 + 2];
        const float dot = ddx * rx + ddy * ry + ddz * rz;

        sA[nl][k] = amp[bn] * dot * corr / denom;
    }
    __syncthreads();

    // ---- main loop: 16 n rows for this group, fully unrolled ----
    float2 acc[KK];
    #pragma unroll
    for (int k = 0; k < KK; ++k) { acc[k].x = 0.0f; acc[k].y = 0.0f; }

    const float4* s4 = (const float4*)sA;
    #pragma unroll
    for (int i = 0; i < 16; ++i) {
        const int nl = ng * 16 + i;
        const float2 ev = (i < 8) ? pf[i] : envp[(size_t)i * (TT / 2)];
        const float4 a0 = s4[nl * 3 + 0];
        const float4 a1 = s4[nl * 3 + 1];
        const float  a8 = sA[nl][8];
        acc[0].x += a0.x * ev.x; acc[0].y += a0.x * ev.y;
        acc[1].x += a0.y * ev.x; acc[1].y += a0.y * ev.y;
        acc[2].x += a0.z * ev.x; acc[2].y += a0.z * ev.y;
        acc[3].x += a0.w * ev.x; acc[3].y += a0.w * ev.y;
        acc[4].x += a1.x * ev.x; acc[4].y += a1.x * ev.y;
        acc[5].x += a1.y * ev.x; acc[5].y += a1.y * ev.y;
        acc[6].x += a1.z * ev.x; acc[6].y += a1.z * ev.y;
        acc[7].x += a1.w * ev.x; acc[7].y += a1.w * ev.y;
        acc[8].x += a8   * ev.x; acc[8].y += a8   * ev.y;
    }

    #pragma unroll
    for (int k = 0; k < KK; ++k) sP[ng][k][tp] = acc[k];
    __syncthreads();

    // ---- group 0's threads fold the two halves and write partial ----
    if (tid < 256) {
        float2* pp = (float2*)(partial + (((size_t)chunk * BB + b) * KK) * TT) + tp;
        #pragma unroll
        for (int k = 0; k < KK; ++k) {
            const float2 u = sP[0][k][tp];
            const float2 v = sP[1][k][tp];
            float2 w; w.x = u.x + v.x; w.y = u.y + v.y;
            pp[(size_t)k * (TT / 2)] = w;
        }
    }
    __syncthreads();                 // all partial stores issued+drained

    if (tid == 0) {
        __threadfence();             // release: partials visible device-wide
        __hip_atomic_fetch_add(&counter[b], 1u, __ATOMIC_RELEASE,
                               __HIP_MEMORY_SCOPE_AGENT);
    }

    if (chunk >= 16) return;         // 16 finalize blocks per b

    // ---- acquire-spin until all 32 chunks of this b are complete ----
    if (tid == 0) {
        unsigned int v;
        long long guard = 0;
        do {
            v = __hip_atomic_load(&counter[b], __ATOMIC_ACQUIRE,
                                  __HIP_MEMORY_SCOPE_AGENT);
            if (++guard > (1LL << 30)) break;   // safety valve: never hang
            __builtin_amdgcn_s_sleep(4);
        } while (v < (unsigned int)NCHUNK);
    }
    __syncthreads();
    __threadfence();

    // ---- finalize t-slice [chunk*32, chunk*32+32) ----
    const int t0  = chunk * 32;
    const int tl4 = tid & 7;        // float4 slot
    const int cg  = tid >> 3;       // 0..31 = source chunk

    if (tid < 256) {
        const float* base = partial + (((size_t)cg * BB + b) * KK) * TT + t0 + tl4 * 4;
        #pragma unroll
        for (int k = 0; k < KK; ++k)
            sV[cg][k][tl4] = *(const float4*)(base + (size_t)k * TT);
    }
    __syncthreads();

    if (tid < KK * 8) {             // 72 threads: reduce 32 chunks
        const int k  = tid >> 3;
        const int tl = tid & 7;
        float4 v = make_float4(0.f, 0.f, 0.f, 0.f);
        #pragma unroll
        for (int g = 0; g < NCHUNK; ++g) {
            const float4 u = sV[g][k][tl];
            v.x += u.x; v.y += u.y; v.z += u.z; v.w += u.w;
        }
        sRf[k][tl * 4 + 0] = fminf(fmaxf(v.x, -50.0f), 50.0f);
        sRf[k][tl * 4 + 1] = fminf(fmaxf(v.y, -50.0f), 50.0f);
        sRf[k][tl * 4 + 2] = fminf(fmaxf(v.z, -50.0f), 50.0f);
        sRf[k][tl * 4 + 3] = fminf(fmaxf(v.w, -50.0f), 50.0f);
    }
    __syncthreads();

    if (tid < 32) {
        const int t = t0 + tid;
        float V[KK];
        #pragma unroll
        for (int k = 0; k < KK; ++k) V[k] = sRf[k][tid];

        float* vleads = out;                        // (B,12,T)
        float* velec  = out + (size_t)BB * 12 * TT; // (B,K,T)

        #pragma unroll
        for (int k = 0; k < KK; ++k)
            velec[((size_t)b * KK + k) * TT + t] = V[k];

        const float RA = V[0], LA = V[1], LL = V[2];
        const float WCT = (RA + LA + LL) * (1.0f / 3.0f);

        float L[12];
        L[0] = LA - RA;
        L[1] = LL - RA;
        L[2] = LL - LA;
        L[3] = RA - 0.5f * (LA + LL);
        L[4] = LA - 0.5f * (RA + LL);
        L[5] = LL - 0.5f * (RA + LA);
        L[6]  = V[3] - WCT;
        L[7]  = V[4] - WCT;
        L[8]  = V[5] - WCT;
        L[9]  = V[6] - WCT;
        L[10] = V[7] - WCT;
        L[11] = V[8] - WCT;

        #pragma unroll
        for (int l = 0; l < 12; ++l)
            vleads[((size_t)b * 12 + l) * TT + t] = L[l];
    }
}

extern "C" void kernel_launch(void* const* d_in, const int* in_sizes, int n_in,
                              void* d_out, int out_size, void* d_ws, size_t ws_size,
                              hipStream_t stream) {
    const float* pos  = (const float*)d_in[0];
    const float* dd   = (const float*)d_in[1];
    const float* amp  = (const float*)d_in[2];
    const float* env  = (const float*)d_in[3];
    const float* eoff = (const float*)d_in[4];
    const float* W1   = (const float*)d_in[5];
    const float* b1   = (const float*)d_in[6];
    const float* W2   = (const float*)d_in[7];
    const float* b2   = (const float*)d_in[8];
    float* out = (float*)d_out;

    float*        partial = (float*)d_ws;                      // 4.7 MB
    unsigned int* counter = (unsigned int*)((char*)d_ws + PARTIAL_FLOATS * sizeof(float));

    // Zero the 8 per-b completion counters (32 B) — graph-capturable memset node.
    hipMemsetAsync(counter, 0, BB * sizeof(unsigned int), stream);

    dim3 grid(NCHUNK, BB);           // 32 x 8 = 256 blocks, 512 threads
    fused_kernel<<<grid, 512, 0, stream>>>(
        pos, dd, amp, env, eoff, W1, b1, W2, b2, partial, counter, out);
}

// Round 9
// 19.206 us; speedup vs baseline: 3.0591x; 3.0591x over previous
//
#include <hip/hip_runtime.h>
#include <hip/hip_bf16.h>
#include <math.h>

// Problem constants
#define BB 8
#define NN 1024
#define TT 512
#define KK 9
#define HH 32

#define NCHUNK 32          // n-chunks (grid.x of phase A)
#define NPER   (NN/NCHUNK) // 32 n per chunk (2 groups of 16)

__constant__ float c_epos[KK][3] = {
    { 0.30f,  0.25f, 0.00f},
    {-0.30f,  0.25f, 0.00f},
    {-0.05f, -0.40f, 0.00f},
    { 0.03f,  0.05f, 0.20f},
    { 0.00f,  0.05f, 0.22f},
    {-0.04f,  0.01f, 0.21f},
    {-0.08f, -0.02f, 0.18f},
    {-0.14f, -0.02f, 0.13f},
    {-0.20f, -0.02f, 0.07f},
};

// Phase A: block (chunk, b), 512 threads = 2 n-groups x 256 t-pair threads.
// All 16 env rows for this thread are register-prefetched BEFORE the MLP
// phase, so the ~1600-cycle MLP hides the L3 latency entirely and the main
// loop is pure register/LDS FMA work.
__global__ __launch_bounds__(512) void fused_kernel(
    const float* __restrict__ pos,   // (B,N,3)
    const float* __restrict__ dd,    // (B,N,3)
    const float* __restrict__ amp,   // (B,N)
    const float* __restrict__ env,   // (B,N,T)
    const float* __restrict__ eoff,  // (B,K,3)
    const float* __restrict__ W1,    // (H,7)
    const float* __restrict__ pb1,   // (H)
    const float* __restrict__ W2,    // (1,H)
    const float* __restrict__ pb2,   // (1)
    float* __restrict__ partial)     // (NCHUNK,B,K,T)
{
    const int tid   = threadIdx.x;
    const int chunk = blockIdx.x;
    const int b     = blockIdx.y;
    const int n0    = chunk * NPER;
    const int ng    = tid >> 8;      // n-group 0/1 (16 n each)
    const int tp    = tid & 255;     // t-pair index (t = 2*tp, 2*tp+1)

    __shared__ float sW1[HH * 7];
    __shared__ float sb1[HH];
    __shared__ float sW2[HH];
    __shared__ float sb2;
    __shared__ float sE[KK][3];
    __shared__ float sA[NPER][12];       // 9 coeffs padded to 12 for float4 reads
    __shared__ float2 sP[2][KK][256];    // cross-group reduce, 36 KB

    if (tid < HH * 7) sW1[tid] = W1[tid];
    if (tid < HH)     { sb1[tid] = pb1[tid]; sW2[tid] = W2[tid]; }
    if (tid < KK * 3) sE[tid / 3][tid % 3] = c_epos[tid / 3][tid % 3] + eoff[b * KK * 3 + tid];
    if (tid == 0)     sb2 = pb2[0];

    // ---- full env register prefetch (independent of MLP -> overlaps it) ----
    const float2* envp = (const float2*)(env + ((size_t)(b * NN + n0 + ng * 16)) * TT) + tp;
    float2 pf[16];
    #pragma unroll
    for (int i = 0; i < 16; ++i) pf[i] = envp[(size_t)i * (TT / 2)];

    __syncthreads();   // weights + sE visible

    if (tid < NPER * KK) {           // 288 MLP evals, one per thread, 1x total
        const int k  = tid % KK;
        const int nl = tid / KK;
        const int bn = b * NN + n0 + nl;

        const float px = pos[bn * 3 + 0];
        const float py = pos[bn * 3 + 1];
        const float pz = pos[bn * 3 + 2];

        const float rx = sE[k][0] - px, ry = sE[k][1] - py, rz = sE[k][2] - pz;
        const float r2 = rx * rx + ry * ry + rz * rz;
        const float d0 = r2 + 0.04f;
        const float denom = d0 * sqrtf(d0);

        const float rdist = fmaxf(sqrtf(r2), 1e-6f);
        const float rinv  = 1.0f / rdist;
        float feat[7];
        feat[0] = px; feat[1] = py; feat[2] = pz;
        feat[3] = rx * rinv; feat[4] = ry * rinv; feat[5] = rz * rinv;
        feat[6] = rdist;

        float raw = sb2;
        #pragma unroll
        for (int j = 0; j < HH; ++j) {
            float s = sb1[j];
            #pragma unroll
            for (int f = 0; f < 7; ++f) s += sW1[j * 7 + f] * feat[f];
            const float g = 0.5f * s * (1.0f + erff(s * 0.70710678118654752f));
            raw += sW2[j] * g;
        }
        const float corr = 1.0f + 0.5f * tanhf(raw);

        const float ddx = dd[bn * 3 + 0], ddy = dd[bn * 3 + 1], ddz = dd[bn * 3 + 2];
        const float dot = ddx * rx + ddy * ry + ddz * rz;

        sA[nl][k] = amp[bn] * dot * corr / denom;
    }
    __syncthreads();

    // ---- main loop: 16 n rows for this group, all operands in reg/LDS ----
    float2 acc[KK];
    #pragma unroll
    for (int k = 0; k < KK; ++k) { acc[k].x = 0.0f; acc[k].y = 0.0f; }

    const float4* s4 = (const float4*)sA;
    #pragma unroll
    for (int i = 0; i < 16; ++i) {
        const int nl = ng * 16 + i;
        const float2 ev = pf[i];
        const float4 a0 = s4[nl * 3 + 0];
        const float4 a1 = s4[nl * 3 + 1];
        const float  a8 = sA[nl][8];
        acc[0].x += a0.x * ev.x; acc[0].y += a0.x * ev.y;
        acc[1].x += a0.y * ev.x; acc[1].y += a0.y * ev.y;
        acc[2].x += a0.z * ev.x; acc[2].y += a0.z * ev.y;
        acc[3].x += a0.w * ev.x; acc[3].y += a0.w * ev.y;
        acc[4].x += a1.x * ev.x; acc[4].y += a1.x * ev.y;
        acc[5].x += a1.y * ev.x; acc[5].y += a1.y * ev.y;
        acc[6].x += a1.z * ev.x; acc[6].y += a1.z * ev.y;
        acc[7].x += a1.w * ev.x; acc[7].y += a1.w * ev.y;
        acc[8].x += a8   * ev.x; acc[8].y += a8   * ev.y;
    }

    #pragma unroll
    for (int k = 0; k < KK; ++k) sP[ng][k][tp] = acc[k];
    __syncthreads();

    // ---- group 0's threads fold the two halves and write partial ----
    if (tid < 256) {
        float2* pp = (float2*)(partial + (((size_t)chunk * BB + b) * KK) * TT) + tp;
        #pragma unroll
        for (int k = 0; k < KK; ++k) {
            const float2 u = sP[0][k][tp];
            const float2 v = sP[1][k][tp];
            float2 w; w.x = u.x + v.x; w.y = u.y + v.y;
            pp[(size_t)k * (TT / 2)] = w;
        }
    }
}

// Finalize: V = clip(sum_c partial, -50, 50); emit leads + V_electrodes.
// grid (16, 8): block covers 32 t; 32 c-groups x 8 float4-slots over t.
__global__ __launch_bounds__(256) void finalize_kernel(
    const float* __restrict__ partial,  // (NCHUNK,B,K,T)
    float* __restrict__ out)            // v_leads (B,12,T) then V_elec (B,K,T)
{
    const int tid = threadIdx.x;
    const int tl4 = tid & 7;        // float4 slot: t = t0 + tl4*4 .. +3
    const int cg  = tid >> 3;       // 0..31 = chunk
    const int tc  = blockIdx.x;     // 0..15
    const int b   = blockIdx.y;
    const int t0  = tc * 32;

    float4 s[KK];
    {
        const float* base = partial + (((size_t)cg * BB + b) * KK) * TT + t0 + tl4 * 4;
        #pragma unroll
        for (int k = 0; k < KK; ++k)
            s[k] = *(const float4*)(base + (size_t)k * TT);
    }

    __shared__ float4 sV[32][KK][8];   // 36 KB
    __shared__ float  sRf[KK][32];
    #pragma unroll
    for (int k = 0; k < KK; ++k) sV[cg][k][tl4] = s[k];
    __syncthreads();

    if (tid < KK * 8) {                // 72 threads: reduce 32 chunks
        const int k  = tid >> 3;
        const int tl = tid & 7;
        float4 v = make_float4(0.f, 0.f, 0.f, 0.f);
        #pragma unroll
        for (int g = 0; g < 32; ++g) {
            const float4 u = sV[g][k][tl];
            v.x += u.x; v.y += u.y; v.z += u.z; v.w += u.w;
        }
        sRf[k][tl * 4 + 0] = fminf(fmaxf(v.x, -50.0f), 50.0f);
        sRf[k][tl * 4 + 1] = fminf(fmaxf(v.y, -50.0f), 50.0f);
        sRf[k][tl * 4 + 2] = fminf(fmaxf(v.z, -50.0f), 50.0f);
        sRf[k][tl * 4 + 3] = fminf(fmaxf(v.w, -50.0f), 50.0f);
    }
    __syncthreads();

    if (tid < 32) {
        const int t = t0 + tid;
        float V[KK];
        #pragma unroll
        for (int k = 0; k < KK; ++k) V[k] = sRf[k][tid];

        float* vleads = out;                        // (B,12,T)
        float* velec  = out + (size_t)BB * 12 * TT; // (B,K,T)

        #pragma unroll
        for (int k = 0; k < KK; ++k)
            velec[((size_t)b * KK + k) * TT + t] = V[k];

        const float RA = V[0], LA = V[1], LL = V[2];
        const float WCT = (RA + LA + LL) * (1.0f / 3.0f);

        float L[12];
        L[0] = LA - RA;
        L[1] = LL - RA;
        L[2] = LL - LA;
        L[3] = RA - 0.5f * (LA + LL);
        L[4] = LA - 0.5f * (RA + LL);
        L[5] = LL - 0.5f * (RA + LA);
        L[6]  = V[3] - WCT;
        L[7]  = V[4] - WCT;
        L[8]  = V[5] - WCT;
        L[9]  = V[6] - WCT;
        L[10] = V[7] - WCT;
        L[11] = V[8] - WCT;

        #pragma unroll
        for (int l = 0; l < 12; ++l)
            vleads[((size_t)b * 12 + l) * TT + t] = L[l];
    }
}

extern "C" void kernel_launch(void* const* d_in, const int* in_sizes, int n_in,
                              void* d_out, int out_size, void* d_ws, size_t ws_size,
                              hipStream_t stream) {
    const float* pos  = (const float*)d_in[0];
    const float* dd   = (const float*)d_in[1];
    const float* amp  = (const float*)d_in[2];
    const float* env  = (const float*)d_in[3];
    const float* eoff = (const float*)d_in[4];
    const float* W1   = (const float*)d_in[5];
    const float* b1   = (const float*)d_in[6];
    const float* W2   = (const float*)d_in[7];
    const float* b2   = (const float*)d_in[8];
    float* out = (float*)d_out;

    float* partial = (float*)d_ws;   // (NCHUNK,B,K,T) floats = 4.7 MB

    {
        dim3 grid(NCHUNK, BB);           // 32 x 8 = 256 blocks, 512 threads
        fused_kernel<<<grid, 512, 0, stream>>>(
            pos, dd, amp, env, eoff, W1, b1, W2, b2, partial);
    }
    {
        dim3 grid(16, BB);               // 128 blocks
        finalize_kernel<<<grid, 256, 0, stream>>>(partial, out);
    }
}